// Round 10
// baseline (98.233 us; speedup 1.0000x reference)
//
#include <hip/hip_runtime.h>
#include <hip/hip_bf16.h>

// MiniBatchDiscrimination via bf16 MFMA (gfx950) — SINGLE fused kernel.
// x: [32,16,16,256] f32, T: [256,64,8] f32, out: [32,16,16,320] f32.
// Grid 1024 = (pixel, t-quarter), 256 thr, 4 blocks/CU (one resident round).
// K-chunked (4 x 64): per chunk, cooperatively stage x->A-frags (bf16, LDS)
// with chunk-predicated passthrough, and T-quarter -> LDS transposed bf16
// [t][k] (coalesced float4 global reads; T is L2/L3-resident). Waves read
// A/B frags via ds_read_b128, 8 MFMA/chunk. Then park M quarter in LDS,
// pairwise exp(-L1), coalesced o_b stores. No d_ws, no second launch.

namespace {
constexpr int kN = 32;
constexpr int kHW = 256;
constexpr int kF = 256;          // GEMM K
constexpr int kOutRow = 320;
constexpr int kChunk = 64;       // K-chunk
constexpr int kTtStride = 72;    // ushorts per t-row in Tt chunk (64 + 8 pad)
constexpr int kMstride = 136;    // ushorts/row: 128 + 8 pad
constexpr int kOstride = 24;     // floats/row in obuf
}

using frag_ab = __attribute__((ext_vector_type(8))) short;   // 8 bf16
using frag_cd = __attribute__((ext_vector_type(4))) float;   // 4 f32

__device__ inline unsigned short f2bf(float f) {
  union { __hip_bfloat16 h; unsigned short u; } c;
  c.h = __float2bfloat16(f);
  return c.u;
}

__device__ inline uint4 pack_bf8(const float4& v0, const float4& v1) {
  uint4 p;
  p.x = (unsigned)f2bf(v0.x) | ((unsigned)f2bf(v0.y) << 16);
  p.y = (unsigned)f2bf(v0.z) | ((unsigned)f2bf(v0.w) << 16);
  p.z = (unsigned)f2bf(v1.x) | ((unsigned)f2bf(v1.y) << 16);
  p.w = (unsigned)f2bf(v1.z) | ((unsigned)f2bf(v1.w) << 16);
  return p;
}

__device__ inline void unpack8(const uint4& m, float* f) {
  f[0] = __uint_as_float(m.x << 16);  f[1] = __uint_as_float(m.x & 0xffff0000u);
  f[2] = __uint_as_float(m.y << 16);  f[3] = __uint_as_float(m.y & 0xffff0000u);
  f[4] = __uint_as_float(m.z << 16);  f[5] = __uint_as_float(m.z & 0xffff0000u);
  f[6] = __uint_as_float(m.w << 16);  f[7] = __uint_as_float(m.w & 0xffff0000u);
}

__global__ __launch_bounds__(256, 4)
void mbd_fused(const float* __restrict__ x, const float* __restrict__ T,
               float* __restrict__ out) {
  __shared__ __align__(16) unsigned short Tt[128 * kTtStride];  // 18 KB chunk
  __shared__ uint4 Af[4 * 64];                                  // 4 KB chunk
  __shared__ __align__(16) unsigned short Mlds[kN * kMstride];  // 8.7 KB
  float* obuf = (float*)Tt;                 // [32][24] alias (Tt dead by then)
  const int hw = blockIdx.x & (kHW - 1);
  const int qg = blockIdx.x >> 8;           // t-quarter 0..3 (128 t-cols)
  const int tid = threadIdx.x;
  const int l = tid & 63, w = tid >> 6;     // 4 waves

  frag_cd acc[2][2] = {};                   // [q][rt]; wave owns local tiles 2w,2w+1

  for (int c = 0; c < 4; ++c) {
    // ---- Stage x chunk -> A-frags + chunk-predicated passthrough ----
    {
      const int n = tid >> 3;               // 0..31
      const int k8l = tid & 7;              // local k-group of 8
      const float* xp = x + ((size_t)(n * kHW + hw) * kF + c * kChunk + k8l * 8);
      float4 v0 = *(const float4*)xp;
      float4 v1 = *(const float4*)(xp + 4);
      if (c == qg) {                        // passthrough written exactly once
        float* op = out + ((size_t)(n * kHW + hw) * kOutRow + c * kChunk + k8l * 8);
        *(float4*)op = v0;
        *(float4*)(op + 4) = v1;
      }
      const int ktl = k8l >> 2;             // 0..1
      const int ln = (n & 15) | ((k8l & 3) << 4);
      Af[((n >> 4) * 2 + ktl) * 64 + ln] = pack_bf8(v0, v1);
    }
    // ---- Stage T chunk transposed: Tt[t_local][k_local] bf16 ----
#pragma unroll
    for (int it = 0; it < 8; ++it) {
      const int g = tid + it * 256;         // 0..2047
      const int k = g >> 5;                 // 0..63
      const int t0 = (g & 31) * 4;          // 0..124
      float4 v = *(const float4*)&T[(size_t)(c * kChunk + k) * 512 + qg * 128 + t0];
      Tt[(t0 + 0) * kTtStride + k] = f2bf(v.x);
      Tt[(t0 + 1) * kTtStride + k] = f2bf(v.y);
      Tt[(t0 + 2) * kTtStride + k] = f2bf(v.z);
      Tt[(t0 + 3) * kTtStride + k] = f2bf(v.w);
    }
    __syncthreads();

    // ---- MFMA: 2 kt x 2 rt x 2 t-tiles = 8 per wave per chunk ----
#pragma unroll
    for (int ktl = 0; ktl < 2; ++ktl) {
      const int kloc = ktl * 32 + (l >> 4) * 8;   // k within chunk for this lane
      uint4 a0 = Af[(0 * 2 + ktl) * 64 + l];
      uint4 a1 = Af[(1 * 2 + ktl) * 64 + l];
      frag_ab af0 = __builtin_bit_cast(frag_ab, a0);
      frag_ab af1 = __builtin_bit_cast(frag_ab, a1);
#pragma unroll
      for (int q = 0; q < 2; ++q) {
        const int tloc = (w * 2 + q) * 16 + (l & 15);
        uint4 b = *(const uint4*)&Tt[tloc * kTtStride + kloc];
        frag_ab bf = __builtin_bit_cast(frag_ab, b);
        acc[q][0] = __builtin_amdgcn_mfma_f32_16x16x32_bf16(af0, bf, acc[q][0], 0, 0, 0);
        acc[q][1] = __builtin_amdgcn_mfma_f32_16x16x32_bf16(af1, bf, acc[q][1], 0, 0, 0);
      }
    }
    __syncthreads();   // Tt/Af consumed; safe to restage next chunk
  }

  // ---- Park M quarter (bf16). C/D: col = l&15 (t), row = (l>>4)*4 + r (n) ----
#pragma unroll
  for (int q = 0; q < 2; ++q)
#pragma unroll
    for (int rt = 0; rt < 2; ++rt)
#pragma unroll
      for (int r = 0; r < 4; ++r) {
        const int n = rt * 16 + (l >> 4) * 4 + r;
        const int t = (w * 2 + q) * 16 + (l & 15);  // local col 0..127
        Mlds[n * kMstride + t] = f2bf(acc[q][rt][r]);
      }
  __syncthreads();

  // ---- Pairwise exp(-L1). Thread: local b = tid>>4 (0..15), i in {i0,i0+1} ----
  const int b = tid >> 4;
  const int i0 = (tid & 15) * 2;
  float mi[2][8];
#pragma unroll
  for (int ii = 0; ii < 2; ++ii) {
    uint4 m = *(const uint4*)&Mlds[(i0 + ii) * kMstride + b * 8];
    unpack8(m, mi[ii]);
  }
  float ob0 = 0.f, ob1 = 0.f;
#pragma unroll 4
  for (int j = 0; j < kN; ++j) {
    uint4 m = *(const uint4*)&Mlds[j * kMstride + b * 8];  // 16-lane broadcast
    float mj[8];
    unpack8(m, mj);
    float n0 = 0.f, n1 = 0.f;
#pragma unroll
    for (int cc = 0; cc < 8; ++cc) {
      n0 += fabsf(mi[0][cc] - mj[cc]);
      n1 += fabsf(mi[1][cc] - mj[cc]);
    }
    ob0 += __expf(-n0);
    ob1 += __expf(-n1);
  }
  obuf[i0 * kOstride + b] = ob0;            // aliased over dead Tt
  obuf[(i0 + 1) * kOstride + b] = ob1;
  __syncthreads();

  // ---- Coalesced o_b stores (32 n x 4 float4 per block) ----
  if (tid < 128) {
    const int n = tid >> 2;
    const int b4 = tid & 3;
    float4 v = *(const float4*)&obuf[n * kOstride + b4 * 4];
    *(float4*)&out[(size_t)(n * kHW + hw) * kOutRow + kF + qg * 16 + b4 * 4] = v;
  }
}

extern "C" void kernel_launch(void* const* d_in, const int* in_sizes, int n_in,
                              void* d_out, int out_size, void* d_ws, size_t ws_size,
                              hipStream_t stream) {
  const float* x = (const float*)d_in[0];   // [32,16,16,256]
  const float* T = (const float*)d_in[1];   // [256,64,8] = [256][512]
  float* out = (float*)d_out;               // [32,16,16,320]
  (void)in_sizes; (void)n_in; (void)out_size; (void)d_ws; (void)ws_size;
  mbd_fused<<<dim3(4 * kHW), dim3(256), 0, stream>>>(x, T, out);
}